// Round 4
// baseline (198.397 us; speedup 1.0000x reference)
//
#include <hip/hip_runtime.h>

typedef unsigned short u16;
typedef unsigned int   u32;

using short8 = __attribute__((ext_vector_type(8))) short;
using f32x4  = __attribute__((ext_vector_type(4))) float;
using half4  = __attribute__((ext_vector_type(4))) _Float16;

// SCALE * log2(e) folded into q at the QKV epilogue
#define QSCALE 0.18033688011112042f

__device__ __forceinline__ u16 f2bf(float f) {
  u32 u = __float_as_uint(f);
  return (u16)((u + 0x8000u) >> 16);
}
__device__ __forceinline__ u16 f2h(float f) {
  _Float16 h = (_Float16)f;
  return __builtin_bit_cast(u16, h);
}

// async global->LDS DMA, 16B per lane; lds dest = wave-uniform base + lane*16
__device__ __forceinline__ void gld16(const u16* g, u16* l) {
  __builtin_amdgcn_global_load_lds(
      (const __attribute__((address_space(1))) unsigned int*)g,
      (__attribute__((address_space(3))) unsigned int*)l, 16, 0, 0);
}

// ---------------- x fp32 -> bf16, 4 elems/thread ----------------
__global__ __launch_bounds__(256) void cvt_x(const float* __restrict__ in,
                                             u16* __restrict__ out) {
  int idx = blockIdx.x * 256 + threadIdx.x;
  float4 v = reinterpret_cast<const float4*>(in)[idx];
  ushort4 o;
  o.x = f2bf(v.x); o.y = f2bf(v.y); o.z = f2bf(v.z); o.w = f2bf(v.w);
  reinterpret_cast<ushort4*>(out)[idx] = o;
}

// ---------------- fp32 [R][C] -> bf16 [C][R] (B^T layout for GEMM) ----------------
__global__ __launch_bounds__(256) void transpose_w(const float* __restrict__ in,
                                                   u16* __restrict__ out,
                                                   int R, int C) {
  __shared__ u32 s[32][33];
  int c0 = blockIdx.x * 32, r0 = blockIdx.y * 32;
  int j = threadIdx.x & 31, i0 = threadIdx.x >> 5;
#pragma unroll
  for (int p = 0; p < 4; ++p) {
    int i = i0 + p * 8;
    s[i][j] = f2bf(in[(size_t)(r0 + i) * C + c0 + j]);
  }
  __syncthreads();
#pragma unroll
  for (int p = 0; p < 4; ++p) {
    int jj = i0 + p * 8;
    out[(size_t)(c0 + jj) * R + r0 + j] = (u16)s[j][jj];
  }
}

// ---------------- bf16 MFMA GEMM: C[M,N] = A[M,K] @ Bt[N,K]^T + bias ----------------
// m97 structure, block tile (32*MT) x 128, BK=32, global_load_lds width-16
// staging with XOR-swizzled LDS. EPI==0 (MT=4): scatter qkv (q pre-scaled by
// SCALE*log2e; v written fp16, tile-swizzled [bh][tile][d][sub^(d&15)] layout).
// EPI==1 (MT=2): fp32 C out.
template <int EPI, int MT>
__global__ __launch_bounds__(256, 3) void gemm_bt(
    const u16* __restrict__ A, const u16* __restrict__ Bt,
    const float* __restrict__ bias, float* __restrict__ c_out,
    u16* __restrict__ q_out, u16* __restrict__ k_out, u16* __restrict__ vt_out,
    int M, int N, int K) {
  __shared__ __align__(16) u16 As[32 * MT * 32];
  __shared__ __align__(16) u16 Bs[128 * 32];
  const int tid = threadIdx.x;
  const int lane = tid & 63;
  const int wv = tid >> 6;
  const int l16 = lane & 15, quad = lane >> 4;
  const int wm = wv & 1, wn = wv >> 1;
  const int bx = blockIdx.x, by = blockIdx.y;

  const u16* Ab = A + (size_t)by * (32 * MT) * K;
  const u16* Bb = Bt + (size_t)bx * 128 * K;

  const f32x4 fzero = {0.0f, 0.0f, 0.0f, 0.0f};
  f32x4 acc[MT][4];
#pragma unroll
  for (int i = 0; i < MT; ++i)
#pragma unroll
    for (int j = 0; j < 4; ++j) acc[i][j] = fzero;

  for (int k0 = 0; k0 < K; k0 += 32) {
    __syncthreads();
#pragma unroll
    for (int p = 0; p < MT / 2; ++p) {
      int id = p * 256 + tid;
      int row = id >> 2, blk = id & 3;
      int gc = k0 + ((blk ^ (row & 3)) << 3);
      gld16(Ab + (size_t)row * K + gc, &As[id << 3]);
    }
#pragma unroll
    for (int p = 0; p < 2; ++p) {
      int id = p * 256 + tid;
      int row = id >> 2, blk = id & 3;
      int gc = k0 + ((blk ^ (row & 3)) << 3);
      gld16(Bb + (size_t)row * K + gc, &Bs[id << 3]);
    }
    __syncthreads();
    short8 af[MT], bfr[4];
#pragma unroll
    for (int mi = 0; mi < MT; ++mi) {
      int row = wm * (MT * 16) + mi * 16 + l16;
      af[mi] = *reinterpret_cast<const short8*>(&As[row * 32 + ((quad ^ (row & 3)) << 3)]);
    }
#pragma unroll
    for (int ni = 0; ni < 4; ++ni) {
      int row = wn * 64 + ni * 16 + l16;
      bfr[ni] = *reinterpret_cast<const short8*>(&Bs[row * 32 + ((quad ^ (row & 3)) << 3)]);
    }
#pragma unroll
    for (int mi = 0; mi < MT; ++mi)
#pragma unroll
      for (int ni = 0; ni < 4; ++ni)
        acc[mi][ni] = __builtin_amdgcn_mfma_f32_16x16x32_bf16(af[mi], bfr[ni], acc[mi][ni], 0, 0, 0);
  }

  // epilogue: C row = quad*4+r (A dim), col = l16 (B dim)
#pragma unroll
  for (int mi = 0; mi < MT; ++mi)
#pragma unroll
    for (int ni = 0; ni < 4; ++ni) {
      int col = bx * 128 + wn * 64 + ni * 16 + l16;
      float bv = bias[col];
      int row0 = by * (32 * MT) + wm * (MT * 16) + mi * 16 + quad * 4;
      if (EPI == 1) {
#pragma unroll
        for (int r = 0; r < 4; ++r)
          c_out[(size_t)(row0 + r) * N + col] = acc[mi][ni][r] + bv;
      } else {
        int which = col >> 10, rem = col & 1023;
        int h = rem >> 6, d = rem & 63;
        int b = row0 >> 11, sq0 = row0 & 2047;
        int bh = (b << 4) + h;
        if (which == 2) {
          // V fp16, tile-swizzled: [bh][t>>6][d][ ((t>>2)&15 ^ (d&15))*4 + (t&3) ]
          int tile = sq0 >> 6;
          int sub = ((sq0 >> 2) & 15) ^ (d & 15);
          ushort4 pk;
          pk.x = f2h(acc[mi][ni][0] + bv);
          pk.y = f2h(acc[mi][ni][1] + bv);
          pk.z = f2h(acc[mi][ni][2] + bv);
          pk.w = f2h(acc[mi][ni][3] + bv);
          *reinterpret_cast<ushort4*>(
              &vt_out[(size_t)bh * 131072 + tile * 4096 + d * 64 + (sub << 2)]) = pk;
        } else {
          size_t base = (size_t)(bh * 2048 + sq0) * 64 + d;
#pragma unroll
          for (int r = 0; r < 4; ++r) {
            float val = acc[mi][ni][r] + bv;
            if (which == 0) q_out[base + r * 64] = f2bf(val * QSCALE);
            else            k_out[base + r * 64] = f2bf(val);
          }
        }
      }
    }
}

// ---------------- flash attention (t-split waves, register P, register Q) ----
// 64 Q rows/block; wave w owns K/V k-slice [w*16, w*16+16) and computes S^T +
// partial O for ALL 64 q. Q B-frags hoisted to registers from global (no Qs
// LDS). Per wave-iter LDS = 2 ka + 4 vb reads = 4 KB (4x less than q-split).
// V tile pre-swizzled in global at 4-short granularity -> conflict-free vb.
// Partial-O reduced across waves once per block via the retired K/V LDS.
__global__ __launch_bounds__(256, 3) void attn(
    const u16* __restrict__ q_buf, const u16* __restrict__ k_buf,
    const u16* __restrict__ vt_buf, u16* __restrict__ o_buf) {
  __shared__ __align__(16) u16 smem[2][2][4096];  // [dbuf][K|V][64*64], 32 KB
  __shared__ __align__(16) float lred[256];       // l partials [w][qi][16]

  const int tid = threadIdx.x;
  const int lane = tid & 63, w = tid >> 6;
  const int l16 = lane & 15, quad = lane >> 4;
  const int bh = blockIdx.y, q0 = blockIdx.x * 64;

  const u16* qg = q_buf + (size_t)bh * 131072 + q0 * 64;
  const u16* kg = k_buf + (size_t)bh * 131072;
  const u16* vg = vt_buf + (size_t)bh * 131072;

  // Q B-frags straight from global: n=q=l16 (per tile), k = kk*32 + quad*8 + j
  short8 qb[4][2];
#pragma unroll
  for (int qi = 0; qi < 4; ++qi)
#pragma unroll
    for (int kk = 0; kk < 2; ++kk)
      qb[qi][kk] = *reinterpret_cast<const short8*>(
          qg + (qi * 16 + l16) * 64 + kk * 32 + quad * 8);

  // stage K0 (xor-swizzled rows) + V0 (linear; pre-swizzled in global)
#pragma unroll
  for (int p = 0; p < 2; ++p) {
    int id = p * 256 + tid;
    int row = id >> 3, blk = id & 7;
    gld16(kg + row * 64 + ((blk ^ (row & 7)) << 3), &smem[0][0][id << 3]);
    gld16(vg + id * 8, &smem[0][1][id << 3]);
  }

  const f32x4 fzero = {0.0f, 0.0f, 0.0f, 0.0f};
  f32x4 o_acc[4][4];
  float l_acc[4] = {0.f, 0.f, 0.f, 0.f};
#pragma unroll
  for (int qi = 0; qi < 4; ++qi)
#pragma unroll
    for (int nd = 0; nd < 4; ++nd) o_acc[qi][nd] = fzero;

  // precomputed LDS offsets (u16 units)
  const int kr = w * 16 + l16;                         // this wave's K rows
  const int ka_off0 = kr * 64 + (((0 * 4 + quad) ^ (kr & 7)) << 3);
  const int ka_off1 = kr * 64 + (((1 * 4 + quad) ^ (kr & 7)) << 3);
  const int vb_off = l16 * 64 + ((((w * 4 + quad) ^ l16)) << 2);

  __syncthreads();  // drain prologue DMA

  for (int i = 0; i < 32; ++i) {
    const int buf = i & 1;
    if (i + 1 < 32) {  // prefetch next K/V tile (drained by end-of-iter barrier)
      const int nxt = buf ^ 1;
#pragma unroll
      for (int p = 0; p < 2; ++p) {
        int id = p * 256 + tid;
        int row = id >> 3, blk = id & 7;
        gld16(kg + ((i + 1) * 64 + row) * 64 + ((blk ^ (row & 7)) << 3),
              &smem[nxt][0][id << 3]);
        gld16(vg + (i + 1) * 4096 + id * 8, &smem[nxt][1][id << 3]);
      }
    }

    // S^T = K.Q^T for this wave's 16 t-rows, all 4 q-tiles
    f32x4 s[4];
#pragma unroll
    for (int qi = 0; qi < 4; ++qi) s[qi] = fzero;
    {
      short8 ka0 = *reinterpret_cast<const short8*>(&smem[buf][0][ka_off0]);
      short8 ka1 = *reinterpret_cast<const short8*>(&smem[buf][0][ka_off1]);
#pragma unroll
      for (int qi = 0; qi < 4; ++qi) {
        s[qi] = __builtin_amdgcn_mfma_f32_16x16x32_bf16(ka0, qb[qi][0], s[qi], 0, 0, 0);
        s[qi] = __builtin_amdgcn_mfma_f32_16x16x32_bf16(ka1, qb[qi][1], s[qi], 0, 0, 0);
      }
    }

    // P = exp2(S^T): lane holds q=l16, t=quad*4+r -> x16 f16 A-frag directly
    half4 pa[4];
#pragma unroll
    for (int qi = 0; qi < 4; ++qi) {
      float p0 = __builtin_amdgcn_exp2f(s[qi][0]);
      float p1 = __builtin_amdgcn_exp2f(s[qi][1]);
      float p2 = __builtin_amdgcn_exp2f(s[qi][2]);
      float p3 = __builtin_amdgcn_exp2f(s[qi][3]);
      l_acc[qi] += (p0 + p1) + (p2 + p3);
      pa[qi][0] = (_Float16)p0; pa[qi][1] = (_Float16)p1;
      pa[qi][2] = (_Float16)p2; pa[qi][3] = (_Float16)p3;
    }

    // O_partial += P.V over this wave's k-slice
#pragma unroll
    for (int nd = 0; nd < 4; ++nd) {
      half4 vb = *reinterpret_cast<const half4*>(&smem[buf][1][vb_off + nd * 1024]);
#pragma unroll
      for (int qi = 0; qi < 4; ++qi)
        o_acc[qi][nd] = __builtin_amdgcn_mfma_f32_16x16x16f16(pa[qi], vb, o_acc[qi][nd], 0, 0, 0);
    }

    __syncthreads();  // drains prefetch DMA + guards buffer reuse
  }

  // ---- cross-wave reduction of O partials and l ----
  // l: quad-reduce within wave, publish per (w, qi)
#pragma unroll
  for (int qi = 0; qi < 4; ++qi) {
    l_acc[qi] += __shfl_xor(l_acc[qi], 16, 64);
    l_acc[qi] += __shfl_xor(l_acc[qi], 32, 64);
  }
  if (lane < 16) {
#pragma unroll
    for (int qi = 0; qi < 4; ++qi) lred[(w * 4 + qi) * 16 + lane] = l_acc[qi];
  }

  float* fb = (float*)smem;
  const int b = bh >> 4, h = bh & 15;

#pragma unroll
  for (int phase = 0; phase < 2; ++phase) {
    // publish this phase's two q-tiles from every wave (32 KB)
#pragma unroll
    for (int qq = 0; qq < 2; ++qq) {
      int qi = phase * 2 + qq;
#pragma unroll
      for (int nd = 0; nd < 4; ++nd)
        *reinterpret_cast<f32x4*>(&fb[((w * 2 + qq) * 4 + nd) * 256 + lane * 4]) =
            o_acc[qi][nd];
    }
    __syncthreads();
    // waves {phase*2, phase*2+1} consume tile qi == w
    if ((w >> 1) == phase) {
      const int sel = w & 1;
      f32x4 lv = fzero;
#pragma unroll
      for (int wp = 0; wp < 4; ++wp)
        lv += *reinterpret_cast<const f32x4*>(&lred[(wp * 4 + w) * 16 + quad * 4]);
      f32x4 os[4];
#pragma unroll
      for (int nd = 0; nd < 4; ++nd) {
        os[nd] = fzero;
#pragma unroll
        for (int wp = 0; wp < 4; ++wp)
          os[nd] += *reinterpret_cast<const f32x4*>(
              &fb[((wp * 2 + sel) * 4 + nd) * 256 + lane * 4]);
      }
#pragma unroll
      for (int r = 0; r < 4; ++r) {
        int sq = q0 + w * 16 + quad * 4 + r;
        float inv = 1.0f / lv[r];
        size_t base = (size_t)(b * 2048 + sq) * 1024 + h * 64;
#pragma unroll
        for (int nd = 0; nd < 4; ++nd)
          o_buf[base + nd * 16 + l16] = f2bf(os[nd][r] * inv);
      }
    }
    __syncthreads();
  }
}

extern "C" void kernel_launch(void* const* d_in, const int* in_sizes, int n_in,
                              void* d_out, int out_size, void* d_ws, size_t ws_size,
                              hipStream_t stream) {
  (void)in_sizes; (void)n_in; (void)out_size; (void)ws_size;
  const float* x     = (const float*)d_in[0];
  const float* W_qkv = (const float*)d_in[1];
  const float* b_qkv = (const float*)d_in[2];
  const float* W_out = (const float*)d_in[3];
  const float* b_out = (const float*)d_in[4];
  float* out = (float*)d_out;

  // workspace layout (48 MB total)
  char* ws = (char*)d_ws;
  u16* x_bf   = (u16*)(ws);              //  8 MB  [4096][1024] bf16
  u16* wqkv_t = (u16*)(ws + 8388608);    //  6 MB  [3072][1024] bf16
  u16* wout_t = (u16*)(ws + 14680064);   //  2 MB  [1024][1024] bf16
  u16* q_buf  = (u16*)(ws + 16777216);   //  8 MB  [32][2048][64] bf16
  u16* k_buf  = (u16*)(ws + 25165824);   //  8 MB  [32][2048][64] bf16
  u16* vt_buf = (u16*)(ws + 33554432);   //  8 MB  [32][32tiles][64][64] fp16 swizzled
  u16* o_bf   = (u16*)(ws + 41943040);   //  8 MB  [4096][1024] bf16

  cvt_x<<<4096, 256, 0, stream>>>(x, x_bf);
  transpose_w<<<dim3(96, 32), 256, 0, stream>>>(W_qkv, wqkv_t, 1024, 3072);
  transpose_w<<<dim3(32, 32), 256, 0, stream>>>(W_out, wout_t, 1024, 1024);
  gemm_bt<0, 4><<<dim3(24, 32), 256, 0, stream>>>(x_bf, wqkv_t, b_qkv, nullptr,
                                                  q_buf, k_buf, vt_buf, 4096, 3072, 1024);
  attn<<<dim3(32, 32), 256, 0, stream>>>(q_buf, k_buf, vt_buf, o_bf);
  gemm_bt<1, 2><<<dim3(8, 64), 256, 0, stream>>>(o_bf, wout_t, b_out, out,
                                                 nullptr, nullptr, nullptr, 4096, 1024, 1024);
}

// Round 5
// 196.765 us; speedup vs baseline: 1.0083x; 1.0083x over previous
//
#include <hip/hip_runtime.h>

typedef unsigned short u16;
typedef unsigned int   u32;

using short8 = __attribute__((ext_vector_type(8))) short;
using f32x4  = __attribute__((ext_vector_type(4))) float;
using half4  = __attribute__((ext_vector_type(4))) _Float16;

// SCALE * log2(e) folded into q at the QKV epilogue
#define QSCALE 0.18033688011112042f

__device__ __forceinline__ u16 f2bf(float f) {
  u32 u = __float_as_uint(f);
  return (u16)((u + 0x8000u) >> 16);
}
__device__ __forceinline__ u16 f2h(float f) {
  _Float16 h = (_Float16)f;
  return __builtin_bit_cast(u16, h);
}

// async global->LDS DMA, 16B per lane; lds dest = wave-uniform base + lane*16
__device__ __forceinline__ void gld16(const u16* g, u16* l) {
  __builtin_amdgcn_global_load_lds(
      (const __attribute__((address_space(1))) unsigned int*)g,
      (__attribute__((address_space(3))) unsigned int*)l, 16, 0, 0);
}

// ---------------- x fp32 -> bf16, 4 elems/thread ----------------
__global__ __launch_bounds__(256) void cvt_x(const float* __restrict__ in,
                                             u16* __restrict__ out) {
  int idx = blockIdx.x * 256 + threadIdx.x;
  float4 v = reinterpret_cast<const float4*>(in)[idx];
  ushort4 o;
  o.x = f2bf(v.x); o.y = f2bf(v.y); o.z = f2bf(v.z); o.w = f2bf(v.w);
  reinterpret_cast<ushort4*>(out)[idx] = o;
}

// ---------------- fp32 [R][C] -> bf16 [C][R] (B^T layout for GEMM) ----------------
__global__ __launch_bounds__(256) void transpose_w(const float* __restrict__ in,
                                                   u16* __restrict__ out,
                                                   int R, int C) {
  __shared__ u32 s[32][33];
  int c0 = blockIdx.x * 32, r0 = blockIdx.y * 32;
  int j = threadIdx.x & 31, i0 = threadIdx.x >> 5;
#pragma unroll
  for (int p = 0; p < 4; ++p) {
    int i = i0 + p * 8;
    s[i][j] = f2bf(in[(size_t)(r0 + i) * C + c0 + j]);
  }
  __syncthreads();
#pragma unroll
  for (int p = 0; p < 4; ++p) {
    int jj = i0 + p * 8;
    out[(size_t)(c0 + jj) * R + r0 + j] = (u16)s[j][jj];
  }
}

// ---------------- bf16 MFMA GEMM: C[M,N] = A[M,K] @ Bt[N,K]^T + bias ----------------
// m97 structure, block tile (32*MT) x 128, BK=32, global_load_lds width-16
// staging with XOR-swizzled LDS. EPI==0 (MT=4): scatter qkv (q pre-scaled by
// SCALE*log2e; v written fp16, tile-swizzled [bh][tile][d][sub^(d&15)] layout).
// EPI==1 (MT=2): fp32 C out.
template <int EPI, int MT>
__global__ __launch_bounds__(256, 3) void gemm_bt(
    const u16* __restrict__ A, const u16* __restrict__ Bt,
    const float* __restrict__ bias, float* __restrict__ c_out,
    u16* __restrict__ q_out, u16* __restrict__ k_out, u16* __restrict__ vt_out,
    int M, int N, int K) {
  __shared__ __align__(16) u16 As[32 * MT * 32];
  __shared__ __align__(16) u16 Bs[128 * 32];
  const int tid = threadIdx.x;
  const int lane = tid & 63;
  const int wv = tid >> 6;
  const int l16 = lane & 15, quad = lane >> 4;
  const int wm = wv & 1, wn = wv >> 1;
  const int bx = blockIdx.x, by = blockIdx.y;

  const u16* Ab = A + (size_t)by * (32 * MT) * K;
  const u16* Bb = Bt + (size_t)bx * 128 * K;

  const f32x4 fzero = {0.0f, 0.0f, 0.0f, 0.0f};
  f32x4 acc[MT][4];
#pragma unroll
  for (int i = 0; i < MT; ++i)
#pragma unroll
    for (int j = 0; j < 4; ++j) acc[i][j] = fzero;

  for (int k0 = 0; k0 < K; k0 += 32) {
    __syncthreads();
#pragma unroll
    for (int p = 0; p < MT / 2; ++p) {
      int id = p * 256 + tid;
      int row = id >> 2, blk = id & 3;
      int gc = k0 + ((blk ^ (row & 3)) << 3);
      gld16(Ab + (size_t)row * K + gc, &As[id << 3]);
    }
#pragma unroll
    for (int p = 0; p < 2; ++p) {
      int id = p * 256 + tid;
      int row = id >> 2, blk = id & 3;
      int gc = k0 + ((blk ^ (row & 3)) << 3);
      gld16(Bb + (size_t)row * K + gc, &Bs[id << 3]);
    }
    __syncthreads();
    short8 af[MT], bfr[4];
#pragma unroll
    for (int mi = 0; mi < MT; ++mi) {
      int row = wm * (MT * 16) + mi * 16 + l16;
      af[mi] = *reinterpret_cast<const short8*>(&As[row * 32 + ((quad ^ (row & 3)) << 3)]);
    }
#pragma unroll
    for (int ni = 0; ni < 4; ++ni) {
      int row = wn * 64 + ni * 16 + l16;
      bfr[ni] = *reinterpret_cast<const short8*>(&Bs[row * 32 + ((quad ^ (row & 3)) << 3)]);
    }
#pragma unroll
    for (int mi = 0; mi < MT; ++mi)
#pragma unroll
      for (int ni = 0; ni < 4; ++ni)
        acc[mi][ni] = __builtin_amdgcn_mfma_f32_16x16x32_bf16(af[mi], bfr[ni], acc[mi][ni], 0, 0, 0);
  }

  // epilogue: C row = quad*4+r (A dim), col = l16 (B dim)
#pragma unroll
  for (int mi = 0; mi < MT; ++mi)
#pragma unroll
    for (int ni = 0; ni < 4; ++ni) {
      int col = bx * 128 + wn * 64 + ni * 16 + l16;
      float bv = bias[col];
      int row0 = by * (32 * MT) + wm * (MT * 16) + mi * 16 + quad * 4;
      if (EPI == 1) {
#pragma unroll
        for (int r = 0; r < 4; ++r)
          c_out[(size_t)(row0 + r) * N + col] = acc[mi][ni][r] + bv;
      } else {
        int which = col >> 10, rem = col & 1023;
        int h = rem >> 6, d = rem & 63;
        int b = row0 >> 11, sq0 = row0 & 2047;
        int bh = (b << 4) + h;
        if (which == 2) {
          // V fp16, tile-swizzled: [bh][t>>6][d][ ((t>>2)&15 ^ (d&15))*4 + (t&3) ]
          int tile = sq0 >> 6;
          int sub = ((sq0 >> 2) & 15) ^ (d & 15);
          ushort4 pk;
          pk.x = f2h(acc[mi][ni][0] + bv);
          pk.y = f2h(acc[mi][ni][1] + bv);
          pk.z = f2h(acc[mi][ni][2] + bv);
          pk.w = f2h(acc[mi][ni][3] + bv);
          *reinterpret_cast<ushort4*>(
              &vt_out[(size_t)bh * 131072 + tile * 4096 + d * 64 + (sub << 2)]) = pk;
        } else {
          size_t base = (size_t)(bh * 2048 + sq0) * 64 + d;
#pragma unroll
          for (int r = 0; r < 4; ++r) {
            float val = acc[mi][ni][r] + bv;
            if (which == 0) q_out[base + r * 64] = f2bf(val * QSCALE);
            else            k_out[base + r * 64] = f2bf(val);
          }
        }
      }
    }
}

// ---------------- flash attention (small blocks, 5 blocks/CU) ----------------
// 32 Q rows/block, 4 waves t-split: wave w owns K/V rows [w*16,w*16+16) of each
// 64-t tile, computes S^T + partial O for all 32 q. Register-resident Q frags
// and P (S^T C-layout == f16 x16 A-layout). LDS = K/V dbuf = exactly 32 KB ->
// 5 blocks/CU; regs capped at 102 via __launch_bounds__(256,5). One barrier
// per iter. l via VALU adds + quad-shfl. Cross-wave O/l reduction per qi-phase
// through the retired LDS (16 KB + 256 B per phase).
__global__ __launch_bounds__(256, 5) void attn(
    const u16* __restrict__ q_buf, const u16* __restrict__ k_buf,
    const u16* __restrict__ vt_buf, u16* __restrict__ o_buf) {
  __shared__ __align__(16) u16 smem[2][2][4096];  // [dbuf][K|V][64*64] = 32768 B

  const int tid = threadIdx.x;
  const int lane = tid & 63, w = tid >> 6;
  const int l16 = lane & 15, quad = lane >> 4;
  const int bh = blockIdx.y, q0 = blockIdx.x * 32;

  const u16* qg = q_buf + (size_t)bh * 131072 + q0 * 64;
  const u16* kg = k_buf + (size_t)bh * 131072;
  const u16* vg = vt_buf + (size_t)bh * 131072;

  // Q B-frags from global: per qi tile: n=q=l16, k = kk*32 + quad*8 + j
  short8 qb[2][2];
#pragma unroll
  for (int qi = 0; qi < 2; ++qi)
#pragma unroll
    for (int kk = 0; kk < 2; ++kk)
      qb[qi][kk] = *reinterpret_cast<const short8*>(
          qg + (qi * 16 + l16) * 64 + kk * 32 + quad * 8);

  // stage K0 (row-xor swizzle) + V0 (linear; pre-swizzled in global)
#pragma unroll
  for (int p = 0; p < 2; ++p) {
    int id = p * 256 + tid;
    int row = id >> 3, blk = id & 7;
    gld16(kg + row * 64 + ((blk ^ (row & 7)) << 3), &smem[0][0][id << 3]);
    gld16(vg + id * 8, &smem[0][1][id << 3]);
  }

  const f32x4 fzero = {0.0f, 0.0f, 0.0f, 0.0f};
  f32x4 o_acc[2][4];
  float l_acc[2] = {0.f, 0.f};
#pragma unroll
  for (int qi = 0; qi < 2; ++qi)
#pragma unroll
    for (int nd = 0; nd < 4; ++nd) o_acc[qi][nd] = fzero;

  // precomputed LDS offsets (u16 units)
  const int kr = w * 16 + l16;  // this wave's K rows within the 64-t tile
  const int ka_off0 = kr * 64 + ((quad ^ (kr & 7)) << 3);
  const int ka_off1 = kr * 64 + (((4 + quad) ^ (kr & 7)) << 3);
  const int vb_off = l16 * 64 + (((w * 4 + quad) ^ l16) << 2);

  __syncthreads();  // drain prologue DMA

  for (int i = 0; i < 32; ++i) {
    const int buf = i & 1;
    if (i + 1 < 32) {  // prefetch next K/V tile (drained by end-of-iter barrier)
      const int nxt = buf ^ 1;
#pragma unroll
      for (int p = 0; p < 2; ++p) {
        int id = p * 256 + tid;
        int row = id >> 3, blk = id & 7;
        gld16(kg + ((i + 1) * 64 + row) * 64 + ((blk ^ (row & 7)) << 3),
              &smem[nxt][0][id << 3]);
        gld16(vg + (i + 1) * 4096 + id * 8, &smem[nxt][1][id << 3]);
      }
    }

    // S^T = K.Q^T for this wave's 16 t-rows, both 16-q tiles
    short8 ka0 = *reinterpret_cast<const short8*>(&smem[buf][0][ka_off0]);
    short8 ka1 = *reinterpret_cast<const short8*>(&smem[buf][0][ka_off1]);
    f32x4 s[2];
#pragma unroll
    for (int qi = 0; qi < 2; ++qi) {
      s[qi] = __builtin_amdgcn_mfma_f32_16x16x32_bf16(ka0, qb[qi][0], fzero, 0, 0, 0);
      s[qi] = __builtin_amdgcn_mfma_f32_16x16x32_bf16(ka1, qb[qi][1], s[qi], 0, 0, 0);
    }

    // P = exp2(S^T): lane holds q=l16, t=quad*4+r -> f16 x16 A-frag directly
    half4 pa[2];
#pragma unroll
    for (int qi = 0; qi < 2; ++qi) {
      float p0 = __builtin_amdgcn_exp2f(s[qi][0]);
      float p1 = __builtin_amdgcn_exp2f(s[qi][1]);
      float p2 = __builtin_amdgcn_exp2f(s[qi][2]);
      float p3 = __builtin_amdgcn_exp2f(s[qi][3]);
      l_acc[qi] += (p0 + p1) + (p2 + p3);
      pa[qi][0] = (_Float16)p0; pa[qi][1] = (_Float16)p1;
      pa[qi][2] = (_Float16)p2; pa[qi][3] = (_Float16)p3;
    }

    // O_partial += P.V over this wave's t-slice
#pragma unroll
    for (int nd = 0; nd < 4; ++nd) {
      half4 vb = *reinterpret_cast<const half4*>(&smem[buf][1][vb_off + nd * 1024]);
#pragma unroll
      for (int qi = 0; qi < 2; ++qi)
        o_acc[qi][nd] = __builtin_amdgcn_mfma_f32_16x16x16f16(pa[qi], vb, o_acc[qi][nd], 0, 0, 0);
    }

    __syncthreads();  // drains prefetch DMA + guards buffer reuse
  }

  // l: reduce across quads -> every lane holds full-wave l for q=l16
#pragma unroll
  for (int qi = 0; qi < 2; ++qi) {
    l_acc[qi] += __shfl_xor(l_acc[qi], 16, 64);
    l_acc[qi] += __shfl_xor(l_acc[qi], 32, 64);
  }

  // cross-wave O/l reduction per qi-phase through retired LDS
  float* fb = (float*)smem;
  const int b = bh >> 4, h = bh & 15;
#pragma unroll
  for (int qi = 0; qi < 2; ++qi) {
    // publish O partial (16 KB) + l partial (256 B @ f32 offset 4096)
#pragma unroll
    for (int nd = 0; nd < 4; ++nd)
      *reinterpret_cast<f32x4*>(&fb[((w * 4 + nd) * 64 + lane) * 4]) = o_acc[qi][nd];
    if (lane < 16) fb[4096 + w * 16 + lane] = l_acc[qi];
    __syncthreads();
    // wave w reduces & writes d-columns [w*16, w*16+16)
    f32x4 os = fzero, lv = fzero;
#pragma unroll
    for (int wp = 0; wp < 4; ++wp) {
      os += *reinterpret_cast<const f32x4*>(&fb[((wp * 4 + w) * 64 + lane) * 4]);
      lv += *reinterpret_cast<const f32x4*>(&fb[4096 + wp * 16 + quad * 4]);
    }
#pragma unroll
    for (int r = 0; r < 4; ++r) {
      int sq = q0 + qi * 16 + quad * 4 + r;
      o_buf[(size_t)(b * 2048 + sq) * 1024 + h * 64 + w * 16 + l16] =
          f2bf(os[r] / lv[r]);
    }
    __syncthreads();
  }
}

extern "C" void kernel_launch(void* const* d_in, const int* in_sizes, int n_in,
                              void* d_out, int out_size, void* d_ws, size_t ws_size,
                              hipStream_t stream) {
  (void)in_sizes; (void)n_in; (void)out_size; (void)ws_size;
  const float* x     = (const float*)d_in[0];
  const float* W_qkv = (const float*)d_in[1];
  const float* b_qkv = (const float*)d_in[2];
  const float* W_out = (const float*)d_in[3];
  const float* b_out = (const float*)d_in[4];
  float* out = (float*)d_out;

  // workspace layout (48 MB total)
  char* ws = (char*)d_ws;
  u16* x_bf   = (u16*)(ws);              //  8 MB  [4096][1024] bf16
  u16* wqkv_t = (u16*)(ws + 8388608);    //  6 MB  [3072][1024] bf16
  u16* wout_t = (u16*)(ws + 14680064);   //  2 MB  [1024][1024] bf16
  u16* q_buf  = (u16*)(ws + 16777216);   //  8 MB  [32][2048][64] bf16
  u16* k_buf  = (u16*)(ws + 25165824);   //  8 MB  [32][2048][64] bf16
  u16* vt_buf = (u16*)(ws + 33554432);   //  8 MB  [32][32tiles][64][64] fp16 swizzled
  u16* o_bf   = (u16*)(ws + 41943040);   //  8 MB  [4096][1024] bf16

  cvt_x<<<4096, 256, 0, stream>>>(x, x_bf);
  transpose_w<<<dim3(96, 32), 256, 0, stream>>>(W_qkv, wqkv_t, 1024, 3072);
  transpose_w<<<dim3(32, 32), 256, 0, stream>>>(W_out, wout_t, 1024, 1024);
  gemm_bt<0, 4><<<dim3(24, 32), 256, 0, stream>>>(x_bf, wqkv_t, b_qkv, nullptr,
                                                  q_buf, k_buf, vt_buf, 4096, 3072, 1024);
  attn<<<dim3(64, 32), 256, 0, stream>>>(q_buf, k_buf, vt_buf, o_bf);
  gemm_bt<1, 2><<<dim3(8, 64), 256, 0, stream>>>(o_bf, wout_t, b_out, out,
                                                 nullptr, nullptr, nullptr, 4096, 1024, 1024);
}

// Round 6
// 188.864 us; speedup vs baseline: 1.0505x; 1.0418x over previous
//
#include <hip/hip_runtime.h>

typedef unsigned short u16;
typedef unsigned int   u32;

using short8 = __attribute__((ext_vector_type(8))) short;
using f32x4  = __attribute__((ext_vector_type(4))) float;
using half4  = __attribute__((ext_vector_type(4))) _Float16;
using half8  = __attribute__((ext_vector_type(8))) _Float16;

// SCALE * log2(e) folded into q at the QKV epilogue
#define QSCALE 0.18033688011112042f

__device__ __forceinline__ u16 f2bf(float f) {
  u32 u = __float_as_uint(f);
  return (u16)((u + 0x8000u) >> 16);
}
__device__ __forceinline__ u16 f2h(float f) {
  _Float16 h = (_Float16)f;
  return __builtin_bit_cast(u16, h);
}

// async global->LDS DMA, 16B per lane; lds dest = wave-uniform base + lane*16
__device__ __forceinline__ void gld16(const u16* g, u16* l) {
  __builtin_amdgcn_global_load_lds(
      (const __attribute__((address_space(1))) unsigned int*)g,
      (__attribute__((address_space(3))) unsigned int*)l, 16, 0, 0);
}

// ---------------- x fp32 -> bf16, 4 elems/thread ----------------
__global__ __launch_bounds__(256) void cvt_x(const float* __restrict__ in,
                                             u16* __restrict__ out) {
  int idx = blockIdx.x * 256 + threadIdx.x;
  float4 v = reinterpret_cast<const float4*>(in)[idx];
  ushort4 o;
  o.x = f2bf(v.x); o.y = f2bf(v.y); o.z = f2bf(v.z); o.w = f2bf(v.w);
  reinterpret_cast<ushort4*>(out)[idx] = o;
}

// ---------------- fp32 [R][C] -> bf16 [C][R] (B^T layout for GEMM) ----------------
__global__ __launch_bounds__(256) void transpose_w(const float* __restrict__ in,
                                                   u16* __restrict__ out,
                                                   int R, int C) {
  __shared__ u32 s[32][33];
  int c0 = blockIdx.x * 32, r0 = blockIdx.y * 32;
  int j = threadIdx.x & 31, i0 = threadIdx.x >> 5;
#pragma unroll
  for (int p = 0; p < 4; ++p) {
    int i = i0 + p * 8;
    s[i][j] = f2bf(in[(size_t)(r0 + i) * C + c0 + j]);
  }
  __syncthreads();
#pragma unroll
  for (int p = 0; p < 4; ++p) {
    int jj = i0 + p * 8;
    out[(size_t)(c0 + jj) * R + r0 + j] = (u16)s[j][jj];
  }
}

// ---------------- bf16 MFMA GEMM: C[M,N] = A[M,K] @ Bt[N,K]^T + bias ----------------
// m97 structure, block tile (32*MT) x 128, BK=32, global_load_lds width-16
// staging with XOR-swizzled LDS. EPI==0 (MT=4): scatter qkv (q pre-scaled by
// SCALE*log2e; v written fp16 in 16-half-contiguous frag layout:
// off = ((t>>2)*16 + (d&15))*16 + (d>>4)*4 + (t&3)). EPI==1 (MT=2): fp32 C out.
template <int EPI, int MT>
__global__ __launch_bounds__(256, 3) void gemm_bt(
    const u16* __restrict__ A, const u16* __restrict__ Bt,
    const float* __restrict__ bias, float* __restrict__ c_out,
    u16* __restrict__ q_out, u16* __restrict__ k_out, u16* __restrict__ vt_out,
    int M, int N, int K) {
  __shared__ __align__(16) u16 As[32 * MT * 32];
  __shared__ __align__(16) u16 Bs[128 * 32];
  const int tid = threadIdx.x;
  const int lane = tid & 63;
  const int wv = tid >> 6;
  const int l16 = lane & 15, quad = lane >> 4;
  const int wm = wv & 1, wn = wv >> 1;
  const int bx = blockIdx.x, by = blockIdx.y;

  const u16* Ab = A + (size_t)by * (32 * MT) * K;
  const u16* Bb = Bt + (size_t)bx * 128 * K;

  const f32x4 fzero = {0.0f, 0.0f, 0.0f, 0.0f};
  f32x4 acc[MT][4];
#pragma unroll
  for (int i = 0; i < MT; ++i)
#pragma unroll
    for (int j = 0; j < 4; ++j) acc[i][j] = fzero;

  for (int k0 = 0; k0 < K; k0 += 32) {
    __syncthreads();
#pragma unroll
    for (int p = 0; p < MT / 2; ++p) {
      int id = p * 256 + tid;
      int row = id >> 2, blk = id & 3;
      int gc = k0 + ((blk ^ (row & 3)) << 3);
      gld16(Ab + (size_t)row * K + gc, &As[id << 3]);
    }
#pragma unroll
    for (int p = 0; p < 2; ++p) {
      int id = p * 256 + tid;
      int row = id >> 2, blk = id & 3;
      int gc = k0 + ((blk ^ (row & 3)) << 3);
      gld16(Bb + (size_t)row * K + gc, &Bs[id << 3]);
    }
    __syncthreads();
    short8 af[MT], bfr[4];
#pragma unroll
    for (int mi = 0; mi < MT; ++mi) {
      int row = wm * (MT * 16) + mi * 16 + l16;
      af[mi] = *reinterpret_cast<const short8*>(&As[row * 32 + ((quad ^ (row & 3)) << 3)]);
    }
#pragma unroll
    for (int ni = 0; ni < 4; ++ni) {
      int row = wn * 64 + ni * 16 + l16;
      bfr[ni] = *reinterpret_cast<const short8*>(&Bs[row * 32 + ((quad ^ (row & 3)) << 3)]);
    }
#pragma unroll
    for (int mi = 0; mi < MT; ++mi)
#pragma unroll
      for (int ni = 0; ni < 4; ++ni)
        acc[mi][ni] = __builtin_amdgcn_mfma_f32_16x16x32_bf16(af[mi], bfr[ni], acc[mi][ni], 0, 0, 0);
  }

  // epilogue: C row = quad*4+r (A dim), col = l16 (B dim)
#pragma unroll
  for (int mi = 0; mi < MT; ++mi)
#pragma unroll
    for (int ni = 0; ni < 4; ++ni) {
      int col = bx * 128 + wn * 64 + ni * 16 + l16;
      float bv = bias[col];
      int row0 = by * (32 * MT) + wm * (MT * 16) + mi * 16 + quad * 4;
      if (EPI == 1) {
#pragma unroll
        for (int r = 0; r < 4; ++r)
          c_out[(size_t)(row0 + r) * N + col] = acc[mi][ni][r] + bv;
      } else {
        int which = col >> 10, rem = col & 1023;
        int h = rem >> 6, d = rem & 63;
        int b = row0 >> 11, sq0 = row0 & 2047;
        int bh = (b << 4) + h;
        if (which == 2) {
          // V fp16 frag layout: 4 consecutive t -> one 8B store
          ushort4 pk;
          pk.x = f2h(acc[mi][ni][0] + bv);
          pk.y = f2h(acc[mi][ni][1] + bv);
          pk.z = f2h(acc[mi][ni][2] + bv);
          pk.w = f2h(acc[mi][ni][3] + bv);
          size_t off = (size_t)bh * 131072 +
                       (((sq0 >> 2) * 16 + (d & 15)) * 16 + ((d >> 4) << 2));
          *reinterpret_cast<ushort4*>(&vt_out[off]) = pk;
        } else {
          size_t base = (size_t)(bh * 2048 + sq0) * 64 + d;
#pragma unroll
          for (int r = 0; r < 4; ++r) {
            float val = acc[mi][ni][r] + bv;
            if (which == 0) q_out[base + r * 64] = f2bf(val * QSCALE);
            else            k_out[base + r * 64] = f2bf(val);
          }
        }
      }
    }
}

// ---------------- flash attention (register-direct K/V, zero-barrier loop) ----
// 64 Q rows/block, 4 waves t-split: wave w owns t-rows [w*16,w*16+16) of each
// 64-t tile for ALL 64 q. K and V are never shared between waves -> no LDS in
// the main loop: frags load straight to registers, prefetched 1 tile ahead
// (compiler emits fine-grained vmcnt pipeline). NO __syncthreads in the loop.
// P register-resident (S^T C-layout == f16 x16 A-layout). Cross-wave O/l
// reduction once at the end via 16 KB LDS. Grid (bh, qtile): all 32 blocks of
// a bh share an XCD (lin%8 == bh%8) -> K/V stay in that XCD's L2.
__global__ __launch_bounds__(256, 3) void attn(
    const u16* __restrict__ q_buf, const u16* __restrict__ k_buf,
    const u16* __restrict__ vt_buf, u16* __restrict__ o_buf) {
  __shared__ __align__(16) float red[4][4][256];  // [w][nd][lane*4], 16 KB
  __shared__ float lred[4][16];

  const int tid = threadIdx.x;
  const int lane = tid & 63, w = tid >> 6;
  const int l16 = lane & 15, quad = lane >> 4;
  const int bh = blockIdx.x, q0 = blockIdx.y * 64;

  const u16* qg = q_buf + (size_t)bh * 131072 + q0 * 64;
  const u16* kp = k_buf + (size_t)bh * 131072 + (w * 16 + l16) * 64 + quad * 8;
  const u16* vp = vt_buf + (size_t)bh * 131072 + ((w * 4 + quad) * 16 + l16) * 16;

  // Q B-frags (loop-invariant): per qi tile n=q=l16, k = kk*32 + quad*8 + j
  short8 qb[4][2];
#pragma unroll
  for (int qi = 0; qi < 4; ++qi)
#pragma unroll
    for (int kk = 0; kk < 2; ++kk)
      qb[qi][kk] = *reinterpret_cast<const short8*>(
          qg + (qi * 16 + l16) * 64 + kk * 32 + quad * 8);

  const f32x4 fzero = {0.0f, 0.0f, 0.0f, 0.0f};
  f32x4 o_acc[4][4];
  float l_acc[4] = {0.f, 0.f, 0.f, 0.f};
#pragma unroll
  for (int qi = 0; qi < 4; ++qi)
#pragma unroll
    for (int nd = 0; nd < 4; ++nd) o_acc[qi][nd] = fzero;

  // prologue: load tile-0 frags
  short8 ka[2][2];
  half8  vf[2][2];
  ka[0][0] = *reinterpret_cast<const short8*>(kp);
  ka[0][1] = *reinterpret_cast<const short8*>(kp + 32);
  vf[0][0] = *reinterpret_cast<const half8*>(vp);
  vf[0][1] = *reinterpret_cast<const half8*>(vp + 8);

#pragma unroll 2
  for (int i = 0; i < 32; ++i) {
    const int buf = i & 1, nb = buf ^ 1;
    if (i + 1 < 32) {  // prefetch next tile's frags (registers, vmcnt-pipelined)
      const u16* kn = kp + (size_t)4096;
      const u16* vn = vp + (size_t)4096;
      ka[nb][0] = *reinterpret_cast<const short8*>(kn);
      ka[nb][1] = *reinterpret_cast<const short8*>(kn + 32);
      vf[nb][0] = *reinterpret_cast<const half8*>(vn);
      vf[nb][1] = *reinterpret_cast<const half8*>(vn + 8);
      kp = kn; vp = vn;
    }

    // S^T = K.Q^T for this wave's 16 t-rows, all 4 q-tiles; P = exp2 in-register
    short8 k0 = ka[buf][0], k1 = ka[buf][1];
    half4 pa[4];
#pragma unroll
    for (int qi = 0; qi < 4; ++qi) {
      f32x4 s = __builtin_amdgcn_mfma_f32_16x16x32_bf16(k0, qb[qi][0], fzero, 0, 0, 0);
      s = __builtin_amdgcn_mfma_f32_16x16x32_bf16(k1, qb[qi][1], s, 0, 0, 0);
      float p0 = __builtin_amdgcn_exp2f(s[0]);
      float p1 = __builtin_amdgcn_exp2f(s[1]);
      float p2 = __builtin_amdgcn_exp2f(s[2]);
      float p3 = __builtin_amdgcn_exp2f(s[3]);
      l_acc[qi] += (p0 + p1) + (p2 + p3);
      pa[qi][0] = (_Float16)p0; pa[qi][1] = (_Float16)p1;
      pa[qi][2] = (_Float16)p2; pa[qi][3] = (_Float16)p3;
    }

    // O_partial += P.V over this wave's t-slice (B-frags from the half8 pair)
    half4 vb0 = __builtin_shufflevector(vf[buf][0], vf[buf][0], 0, 1, 2, 3);
    half4 vb1 = __builtin_shufflevector(vf[buf][0], vf[buf][0], 4, 5, 6, 7);
    half4 vb2 = __builtin_shufflevector(vf[buf][1], vf[buf][1], 0, 1, 2, 3);
    half4 vb3 = __builtin_shufflevector(vf[buf][1], vf[buf][1], 4, 5, 6, 7);
#pragma unroll
    for (int qi = 0; qi < 4; ++qi) {
      o_acc[qi][0] = __builtin_amdgcn_mfma_f32_16x16x16f16(pa[qi], vb0, o_acc[qi][0], 0, 0, 0);
      o_acc[qi][1] = __builtin_amdgcn_mfma_f32_16x16x16f16(pa[qi], vb1, o_acc[qi][1], 0, 0, 0);
      o_acc[qi][2] = __builtin_amdgcn_mfma_f32_16x16x16f16(pa[qi], vb2, o_acc[qi][2], 0, 0, 0);
      o_acc[qi][3] = __builtin_amdgcn_mfma_f32_16x16x16f16(pa[qi], vb3, o_acc[qi][3], 0, 0, 0);
    }
  }

  // l: reduce across quads -> every lane holds this wave's l for q=l16
#pragma unroll
  for (int qi = 0; qi < 4; ++qi) {
    l_acc[qi] += __shfl_xor(l_acc[qi], 16, 64);
    l_acc[qi] += __shfl_xor(l_acc[qi], 32, 64);
  }

  // cross-wave O/l reduction per qi-phase through LDS
  const int b = bh >> 4, h = bh & 15;
#pragma unroll
  for (int qi = 0; qi < 4; ++qi) {
#pragma unroll
    for (int nd = 0; nd < 4; ++nd)
      *reinterpret_cast<f32x4*>(&red[w][nd][lane * 4]) = o_acc[qi][nd];
    if (lane < 16) lred[w][lane] = l_acc[qi];
    __syncthreads();
    // wave w reduces & writes d-columns [w*16, w*16+16)
    f32x4 os = fzero, lv = fzero;
#pragma unroll
    for (int wp = 0; wp < 4; ++wp) {
      os += *reinterpret_cast<const f32x4*>(&red[wp][w][lane * 4]);
      lv += *reinterpret_cast<const f32x4*>(&lred[wp][quad * 4]);
    }
#pragma unroll
    for (int r = 0; r < 4; ++r) {
      int sq = q0 + qi * 16 + quad * 4 + r;
      o_buf[(size_t)(b * 2048 + sq) * 1024 + h * 64 + w * 16 + l16] =
          f2bf(os[r] / lv[r]);
    }
    __syncthreads();
  }
}

extern "C" void kernel_launch(void* const* d_in, const int* in_sizes, int n_in,
                              void* d_out, int out_size, void* d_ws, size_t ws_size,
                              hipStream_t stream) {
  (void)in_sizes; (void)n_in; (void)out_size; (void)ws_size;
  const float* x     = (const float*)d_in[0];
  const float* W_qkv = (const float*)d_in[1];
  const float* b_qkv = (const float*)d_in[2];
  const float* W_out = (const float*)d_in[3];
  const float* b_out = (const float*)d_in[4];
  float* out = (float*)d_out;

  // workspace layout (48 MB total)
  char* ws = (char*)d_ws;
  u16* x_bf   = (u16*)(ws);              //  8 MB  [4096][1024] bf16
  u16* wqkv_t = (u16*)(ws + 8388608);    //  6 MB  [3072][1024] bf16
  u16* wout_t = (u16*)(ws + 14680064);   //  2 MB  [1024][1024] bf16
  u16* q_buf  = (u16*)(ws + 16777216);   //  8 MB  [32][2048][64] bf16
  u16* k_buf  = (u16*)(ws + 25165824);   //  8 MB  [32][2048][64] bf16
  u16* vt_buf = (u16*)(ws + 33554432);   //  8 MB  [32] V-frag fp16 layout
  u16* o_bf   = (u16*)(ws + 41943040);   //  8 MB  [4096][1024] bf16

  cvt_x<<<4096, 256, 0, stream>>>(x, x_bf);
  transpose_w<<<dim3(96, 32), 256, 0, stream>>>(W_qkv, wqkv_t, 1024, 3072);
  transpose_w<<<dim3(32, 32), 256, 0, stream>>>(W_out, wout_t, 1024, 1024);
  gemm_bt<0, 4><<<dim3(24, 32), 256, 0, stream>>>(x_bf, wqkv_t, b_qkv, nullptr,
                                                  q_buf, k_buf, vt_buf, 4096, 3072, 1024);
  attn<<<dim3(32, 32), 256, 0, stream>>>(q_buf, k_buf, vt_buf, o_bf);
  gemm_bt<1, 2><<<dim3(8, 64), 256, 0, stream>>>(o_bf, wout_t, b_out, out,
                                                 nullptr, nullptr, nullptr, 4096, 1024, 1024);
}